// Round 4
// baseline (159.388 us; speedup 1.0000x reference)
//
#include <hip/hip_runtime.h>

#define AFROMZERO 0.02f
#define AFROMC    0.01f
#define OSF       15.0f
#define LOG2E     1.4426950408889634f
#define EXPMAX2   (50.0f * LOG2E)   // reference clips f_exp at +/-50 (natural-log units)

// zmax_calc with c = 1.0 (as used by likelihood()).
__device__ __forceinline__ float zmax_calc(float a, float b) {
    if (a < AFROMZERO) return fminf(b, 1.0f);          // c=1: (c>b)? b/c : 1
    if (fabsf(a - 1.0f) < AFROMC) return b / (b + 1.0f);
    float d  = (b - 1.0f) * (b - 1.0f) + 4.0f * a * b;
    float zg = 0.5f * (b + 1.0f - sqrtf(d)) / (1.0f - a);
    if (zg > 0.9999f && b > 100.0f) zg = fminf(zg, 1.0f - a / b);
    return zg;
}

// Base-2 per-(param,m) constants:
//   f2(z) = C2 - be2*(1/z) - log2(z) + a*log2(1-z)  ==  f_exp * log2(e)
__device__ __forceinline__ void set_consts2(float a, float b, float mTv,
                                            float& C2, float& be2) {
    float be = b * mTv * mTv;
    float zm = zmax_calc(a, be);
    be2 = be * LOG2E;
    float c = be2 / zm + log2f(zm);
    if (a >= AFROMZERO) c -= a * log2f(1.0f - zm);
    C2 = c;
}

typedef const __attribute__((address_space(1))) void* as1_cvp;
typedef __attribute__((address_space(3))) void* as3_vp;

__global__ __launch_bounds__(256) void lund_weight_kernel(
    const float* __restrict__ z,      // (B, 128, 25)
    const float* __restrict__ mT,     // (B, 128)
    const int*   __restrict__ obs,    // (B, 2) -> mult = obs[2b]
    const float* __restrict__ pa_p,
    const float* __restrict__ pb_p,
    const float* __restrict__ base_p, // (2,)
    float* __restrict__ out)          // (B,)
{
    // Contiguous mirror of the block's 6400 z-floats (rows r0, r0+1) + slack:
    // wave w stages its own floats [1600w, 1600w+1792) -- the 192-float overlap
    // into wave w+1's region writes IDENTICAL bytes (benign duplicate).
    __shared__ float s_z[6656];
    __shared__ float s_part[4];

    const int tid  = threadIdx.x;
    const int lane = tid & 63;
    const int wv   = tid >> 6;        // wave id 0..3
    const int r0   = blockIdx.x * 2;

    const int mult0 = obs[2 * r0];
    const int mult1 = obs[2 * r0 + 2];

    const float* g0 = z + (size_t)r0 * 3200;   // 6400 contiguous floats (2 rows)

    // ---- wave-private async HBM -> LDS staging (no block barrier needed) ----
    const int wbase = wv * 1600;      // wave's float offset in the 6400 region
    int need = (wv < 2) ? (mult0 * 25 - wbase) : (mult1 * 25 - (wbase - 3200));
    need = need < 0 ? 0 : need;       // chunks c=0..6 at 256c; issue iff 256c < need
    #pragma unroll
    for (int c = 0; c < 7; ++c) {
        if ((c << 8) < need) {
            const float* gp = g0 + wbase + (c << 8) + (lane << 2);
            // wave3/chunk6 lanes >=16 would read past the 2-row span (OOB on the
            // final block); their LDS slots are never consumed -> clamp.
            if (wv == 3 && c == 6 && lane >= 16) gp = g0;
            __builtin_amdgcn_global_load_lds((as1_cvp)gp,
                                             (as3_vp)(s_z + wbase + (c << 8)),
                                             16, 0, 0);
        }
    }

    // ---- per-thread (param,m) constants, overlapped with this wave's DMA ----
    const int  half = tid >> 7;       // 0 -> row r0, 1 -> row r0+1
    const int  m    = tid & 127;
    const int  mult = half ? mult1 : mult0;
    const bool live = m < mult;

    const float pa = pa_p[0], pb = pb_p[0];
    const float a0 = base_p[0], b0 = base_p[1];
    const float an = (pa < AFROMZERO) ? 0.0f : pa;
    const float ao = (a0 < AFROMZERO) ? 0.0f : a0;

    const float mTv = mT[(size_t)(r0 + half) * 128 + m];
    float Cn2, ben2, Co2, beo2;
    set_consts2(pa, pb, mTv, Cn2, ben2);
    set_consts2(a0, b0, mTv, Co2, beo2);

    // wait for THIS wave's DMA only (vmcnt is per-wave); no __syncthreads.
    __builtin_amdgcn_s_waitcnt(0x0F70);   // vmcnt(0), lgkm/exp unconstrained
    __builtin_amdgcn_sched_barrier(0);    // keep ds_reads below the wait

    float w = 1.0f;
    if (live) {
        // lanes at stride 25 floats: gcd(25,32)=1 -> 2 lanes/bank, conflict-free
        const float* zp = s_z + 25 * tid;
        float facN = 1.0f, facD = 1.0f;
        #pragma unroll
        for (int k = 0; k < 25; ++k) {
            float zz  = zp[k];
            bool  act = (zz != 0.0f);
            float zs  = act ? zz : 0.5f;
            float rz  = __builtin_amdgcn_rcpf(zs);
            float lz  = __builtin_amdgcn_logf(zs);          // log2
            float l1  = __builtin_amdgcn_logf(1.0f - zs);   // log2
            float fn  = fmaf(-ben2, rz, Cn2) + fmaf(an, l1, -lz);
            float fo  = fmaf(-beo2, rz, Co2) + fmaf(ao, l1, -lz);
            // f_exp <= 0 by construction (z_max is the argmax) -> only the
            // lower clamp can bind; upper clamp dropped.
            fn = fmaxf(fn, -EXPMAX2);
            fo = fmaxf(fo, -EXPMAX2);
            float Ln = __builtin_amdgcn_exp2f(fn);
            float Lo = __builtin_amdgcn_exp2f(fo);
            float fN = (k == 0) ? Ln : (OSF - Ln);
            float fD = (k == 0) ? Lo : (OSF - Lo);
            facN *= act ? fN : 1.0f;
            facD *= act ? fD : 1.0f;
        }
        w = facN / facD;
    }

    // 64-lane product reduction (waves 0/1 -> row r0, waves 2/3 -> row r0+1)
    for (int mask = 1; mask < 64; mask <<= 1)
        w *= __shfl_xor(w, mask, 64);
    if ((tid & 63) == 0) s_part[tid >> 6] = w;
    __syncthreads();
    if (tid == 0)   out[r0]     = s_part[0] * s_part[1];
    if (tid == 128) out[r0 + 1] = s_part[2] * s_part[3];
}

extern "C" void kernel_launch(void* const* d_in, const int* in_sizes, int n_in,
                              void* d_out, int out_size, void* d_ws, size_t ws_size,
                              hipStream_t stream) {
    const float* z    = (const float*)d_in[0];
    const float* mT   = (const float*)d_in[1];
    const int*   obs  = (const int*)d_in[2];
    const float* pa   = (const float*)d_in[3];
    const float* pb   = (const float*)d_in[4];
    const float* base = (const float*)d_in[5];
    float* out = (float*)d_out;

    int B = in_sizes[0] / (128 * 25);   // z is (B, 128, 25)
    lund_weight_kernel<<<B / 2, 256, 0, stream>>>(z, mT, obs, pa, pb, base, out);
}